// Round 3
// baseline (336.622 us; speedup 1.0000x reference)
//
#include <hip/hip_runtime.h>
#include <hip/hip_bf16.h>

#define DM 1024
#define NH 16
#define DK 64
#define BB 8
#define SS 1024
#define MROWS (BB * SS)  // 8192

typedef _Float16 f16;
using f32x4 = __attribute__((ext_vector_type(4))) float;
using f16x8 = __attribute__((ext_vector_type(8))) _Float16;
using f16x4 = __attribute__((ext_vector_type(4))) _Float16;

using lds_ptr_t = __attribute__((address_space(3))) void*;
using glb_ptr_t = const __attribute__((address_space(1))) void*;

__device__ __forceinline__ void glds16(const void* g, void* l) {
  __builtin_amdgcn_global_load_lds((glb_ptr_t)g, (lds_ptr_t)l, 16, 0, 0);
}

// ---------------- cast kernel: fp32 -> fp16, 4 elems/thread ----------------
__global__ __launch_bounds__(256) void cast_kernel(const float* __restrict__ src,
                                                   f16* __restrict__ dst,
                                                   int n) {
  int i = (blockIdx.x * 256 + threadIdx.x) * 4;
  if (i < n) {
    float4 v = *reinterpret_cast<const float4*>(src + i);
    f16x4 o;
    o[0] = (f16)v.x; o[1] = (f16)v.y; o[2] = (f16)v.z; o[3] = (f16)v.w;
    *reinterpret_cast<f16x4*>(dst + i) = o;
  }
}

// ---------------- GEMM: C = A @ B^T + bias --------------------------------
// A[M=8192,K=1024] row-major f16, B[N=1024,K=1024] row-major f16 (nn.Linear W).
// MODE 0: out -> f16, layout [b,h,s,d]   (Q/K)
// MODE 1: out -> f16, layout [b,h,d,s]   (V transposed)
// MODE 2: out -> fp32 row-major [M,N]    (final output)
template <int MODE>
__global__ __launch_bounds__(256) void gemm_bt(const f16* __restrict__ A,
                                               const f16* __restrict__ Bm,
                                               const float* __restrict__ bias,
                                               void* __restrict__ Out) {
  __shared__ f16 As[128 * 32];
  __shared__ f16 Bs[128 * 32];
  const int t = threadIdx.x;
  const int lane = t & 63;
  const int w = t >> 6;  // wave 0..3
  const int wm = w >> 1, wn = w & 1;
  const int bm = blockIdx.x * 128;
  const int bn = blockIdx.y * 128;
  const int l15 = lane & 15;
  const int g = lane >> 4;

  const f16* a0 = A + (size_t)bm * DM;
  const f16* b0 = Bm + (size_t)bn * DM;

  f32x4 acc[4][4] = {};

  const int c0 = w * 64 + lane;        // 16B-chunk index (8 f16), issue 0
  const int c1 = 256 + w * 64 + lane;  // issue 1

  for (int kt = 0; kt < DM / 32; ++kt) {
    const int k0 = kt * 32;
    // stage 8KB A-tile + 8KB B-tile via global_load_lds (16B/lane)
    glds16(a0 + (size_t)(c0 >> 2) * DM + k0 + (c0 & 3) * 8, As + (size_t)(w * 64) * 8);
    glds16(a0 + (size_t)(c1 >> 2) * DM + k0 + (c1 & 3) * 8, As + (size_t)(256 + w * 64) * 8);
    glds16(b0 + (size_t)(c0 >> 2) * DM + k0 + (c0 & 3) * 8, Bs + (size_t)(w * 64) * 8);
    glds16(b0 + (size_t)(c1 >> 2) * DM + k0 + (c1 & 3) * 8, Bs + (size_t)(256 + w * 64) * 8);
    __syncthreads();  // compiler drains vmcnt before barrier

    f16x8 af[4], bfr[4];
#pragma unroll
    for (int m = 0; m < 4; ++m)
      af[m] = *(const f16x8*)(As + (wm * 64 + m * 16 + l15) * 32 + g * 8);
#pragma unroll
    for (int n = 0; n < 4; ++n)
      bfr[n] = *(const f16x8*)(Bs + (wn * 64 + n * 16 + l15) * 32 + g * 8);
#pragma unroll
    for (int m = 0; m < 4; ++m)
#pragma unroll
      for (int n = 0; n < 4; ++n)
        acc[m][n] = __builtin_amdgcn_mfma_f32_16x16x32_f16(af[m], bfr[n], acc[m][n], 0, 0, 0);
    __syncthreads();  // reads done before next overwrite
  }

  // epilogue  (C/D map: col = lane&15, row = (lane>>4)*4 + r)
#pragma unroll
  for (int n = 0; n < 4; ++n) {
    const int j = bn + wn * 64 + n * 16 + l15;
    const float bj = bias[j];
#pragma unroll
    for (int m = 0; m < 4; ++m) {
      const int ib = bm + wm * 64 + m * 16 + g * 4;
#pragma unroll
      for (int r = 0; r < 4; ++r) {
        const int i = ib + r;
        const float val = acc[m][n][r] + bj;
        if (MODE == 0) {
          const int b = i >> 10, s = i & 1023, h = j >> 6, d = j & 63;
          ((f16*)Out)[((size_t)((b * 16 + h) * 1024 + s)) * 64 + d] = (f16)val;
        } else if (MODE == 1) {
          const int b = i >> 10, s = i & 1023, h = j >> 6, d = j & 63;
          ((f16*)Out)[((size_t)((b * 16 + h) * 64 + d)) * 1024 + s] = (f16)val;
        } else {
          ((float*)Out)[(size_t)i * DM + j] = val;
        }
      }
    }
  }
}

// ---------------- fused attention: scores + softmax-over-batch + PV --------
// reference: scores[h,b,q,k]; softmax over axis=1 (BATCH):
//   attn[h,b,q,k] = exp(s[h,b,q,k]) / sum_b' exp(s[h,b',q,k])
// Local in k -> fuse fully. grid (qt=S/32, h=NH), block 512; wave b = batch b.
#define PS 1057  // padded plane stride (dwords)

__global__ __launch_bounds__(512) void attn_kernel(const f16* __restrict__ Qr,
                                                   const f16* __restrict__ Kr,
                                                   const f16* __restrict__ Vt,
                                                   f16* __restrict__ Hd) {
  __shared__ float Sx[8 * PS];     // exp(scores), 8 planes of [32][33]
  __shared__ float Dinv[32 * 33];  // 1/denominator per (q,k)

  const int t = threadIdx.x;
  const int lane = t & 63;
  const int b = t >> 6;  // batch index = wave id
  const int h = blockIdx.y;
  const int qt = blockIdx.x;
  const int l15 = lane & 15;
  const int g = lane >> 4;

  const size_t plane = ((size_t)(b * 16 + h) * 1024) * 64;            // [s][d]
  const f16* Qp = Qr + plane;
  const f16* Kp = Kr + plane;
  const f16* Vp = Vt + ((size_t)(b * 16 + h) * 64) * 1024;            // [d][s]

  // Q fragments in registers for all 32 k-tiles
  f16x8 qf[2][2];
#pragma unroll
  for (int i = 0; i < 2; ++i)
#pragma unroll
    for (int db = 0; db < 2; ++db)
      qf[i][db] = *(const f16x8*)(Qp + (size_t)(qt * 32 + i * 16 + l15) * 64 + db * 32 + g * 8);

  f32x4 oacc[2][4] = {};

  for (int kt = 0; kt < 32; ++kt) {
    // ---- scores S_b[32x32] = Q_b @ K_b^T (contraction d=64)
    f32x4 sacc[2][2] = {};
#pragma unroll
    for (int kf = 0; kf < 2; ++kf)
#pragma unroll
      for (int db = 0; db < 2; ++db) {
        f16x8 kfr = *(const f16x8*)(Kp + (size_t)(kt * 32 + kf * 16 + l15) * 64 + db * 32 + g * 8);
#pragma unroll
        for (int i = 0; i < 2; ++i)
          sacc[i][kf] = __builtin_amdgcn_mfma_f32_16x16x32_f16(qf[i][db], kfr, sacc[i][kf], 0, 0, 0);
      }
    // ---- exp and publish to LDS (C layout: row = g*4+r, col = l15)
#pragma unroll
    for (int i = 0; i < 2; ++i)
#pragma unroll
      for (int kf = 0; kf < 2; ++kf)
#pragma unroll
        for (int r = 0; r < 4; ++r) {
          float e = __expf(sacc[i][kf][r]);
          Sx[b * PS + (i * 16 + g * 4 + r) * 33 + kf * 16 + l15] = e;
        }
    __syncthreads();
    // ---- denominators over batch: 512 threads cover 1024 (q,k) positions
#pragma unroll
    for (int pp = 0; pp < 2; ++pp) {
      const int p = t + pp * 512;
      const int q = p >> 5, k = p & 31;
      float sden = 0.f;
#pragma unroll
      for (int bb2 = 0; bb2 < 8; ++bb2) sden += Sx[bb2 * PS + q * 33 + k];
      Dinv[q * 33 + k] = __builtin_amdgcn_rcpf(sden);
    }
    __syncthreads();
    // ---- P fragments (A-operand: row = l15, 8 contiguous k at g*8) as f16
    f16x8 pf[2];
#pragma unroll
    for (int i = 0; i < 2; ++i) {
      const int row = i * 16 + l15;
      union { f16x8 v; f16 hh[8]; } u;
#pragma unroll
      for (int j = 0; j < 8; ++j) {
        const int k = g * 8 + j;
        u.hh[j] = (f16)(Sx[b * PS + row * 33 + k] * Dinv[row * 33 + k]);
      }
      pf[i] = u.v;
    }
    // ---- O += P @ V  (B-operand: col = d, 8 contiguous s from transposed Vt)
#pragma unroll
    for (int n = 0; n < 4; ++n) {
      f16x8 vf = *(const f16x8*)(Vp + (size_t)(n * 16 + l15) * 1024 + kt * 32 + g * 8);
#pragma unroll
      for (int i = 0; i < 2; ++i)
        oacc[i][n] = __builtin_amdgcn_mfma_f32_16x16x32_f16(pf[i], vf, oacc[i][n], 0, 0, 0);
    }
    __syncthreads();  // protect Sx/Dinv before next tile
  }

  // ---- write heads [b, s, h*64+d] as f16
#pragma unroll
  for (int i = 0; i < 2; ++i)
#pragma unroll
    for (int n = 0; n < 4; ++n)
#pragma unroll
      for (int r = 0; r < 4; ++r) {
        const int srow = qt * 32 + i * 16 + g * 4 + r;
        const int d = n * 16 + l15;
        Hd[((size_t)(b * 1024 + srow)) * 1024 + h * 64 + d] = (f16)oacc[i][n][r];
      }
}

// ---------------- launch ---------------------------------------------------
extern "C" void kernel_launch(void* const* d_in, const int* in_sizes, int n_in,
                              void* d_out, int out_size, void* d_ws, size_t ws_size,
                              hipStream_t stream) {
  const float* x  = (const float*)d_in[0];
  const float* Wq = (const float*)d_in[1];
  const float* bq = (const float*)d_in[2];
  const float* Wk = (const float*)d_in[3];
  const float* bk = (const float*)d_in[4];
  const float* Wv = (const float*)d_in[5];
  const float* bv = (const float*)d_in[6];
  const float* Wo = (const float*)d_in[7];
  const float* bo = (const float*)d_in[8];

  char* ws = (char*)d_ws;
  const size_t MB = 1u << 20;
  f16* xf  = (f16*)(ws + 0 * MB);    // 16 MB (dead after V GEMM; reused as Hd)
  f16* Wqf = (f16*)(ws + 16 * MB);   // 2 MB
  f16* Wkf = (f16*)(ws + 18 * MB);   // 2 MB
  f16* Wvf = (f16*)(ws + 20 * MB);   // 2 MB
  f16* Wof = (f16*)(ws + 22 * MB);   // 2 MB
  f16* Qr  = (f16*)(ws + 24 * MB);   // 16 MB [b,h,s,d]
  f16* Kr  = (f16*)(ws + 40 * MB);   // 16 MB [b,h,s,d]
  f16* Vt  = (f16*)(ws + 56 * MB);   // 16 MB [b,h,d,s]
  f16* Hd  = xf;                     // alias: xf dead once projections done

  // casts
  cast_kernel<<<8192, 256, 0, stream>>>(x, xf, MROWS * DM);
  cast_kernel<<<1024, 256, 0, stream>>>(Wq, Wqf, DM * DM);
  cast_kernel<<<1024, 256, 0, stream>>>(Wk, Wkf, DM * DM);
  cast_kernel<<<1024, 256, 0, stream>>>(Wv, Wvf, DM * DM);
  cast_kernel<<<1024, 256, 0, stream>>>(Wo, Wof, DM * DM);

  // projections
  dim3 gg(MROWS / 128, DM / 128);
  gemm_bt<0><<<gg, 256, 0, stream>>>(xf, Wqf, bq, (void*)Qr);
  gemm_bt<0><<<gg, 256, 0, stream>>>(xf, Wkf, bk, (void*)Kr);
  gemm_bt<1><<<gg, 256, 0, stream>>>(xf, Wvf, bv, (void*)Vt);

  // fused attention (scores + softmax over batch + PV); qt fast -> K/V share L2
  attn_kernel<<<dim3(SS / 32, NH), 512, 0, stream>>>(Qr, Kr, Vt, Hd);

  // output projection -> fp32 d_out
  gemm_bt<2><<<gg, 256, 0, stream>>>(Hd, Wof, bo, d_out);
}